// Round 10
// baseline (163.905 us; speedup 1.0000x reference)
//
#include <hip/hip_runtime.h>
#include <math.h>

#define NB 2
#define NS 1024
#define NC 1024
#define NH 16
#define DIMP 240
#define KSPLIT 8
#define AKH 8           // attention K-split

constexpr float INV_SQRT3 = 0.57735026919f;

// ---------------- Kernel 1: LayerNorm + w_proj transpose (block-split merge) ----------
__global__ __launch_bounds__(256) void pre_kernel(const float* __restrict__ s,
                                                  const float* __restrict__ lnw,
                                                  float* __restrict__ ns,
                                                  const float* __restrict__ wp,
                                                  float* __restrict__ wt) {
    __shared__ float sh[64 * 61];
    int tid = threadIdx.x;
    if (blockIdx.x < NB * NS) {
        int row = blockIdx.x;
        const float4* sp = (const float4*)(s + (size_t)row * NC);
        float4 v = sp[tid];
        float sum = v.x + v.y + v.z + v.w;
        float sq  = v.x*v.x + v.y*v.y + v.z*v.z + v.w*v.w;
        #pragma unroll
        for (int off = 32; off; off >>= 1) {
            sum += __shfl_down(sum, off);
            sq  += __shfl_down(sq, off);
        }
        float* s1 = sh; float* s2 = sh + 4;
        int wave = tid >> 6;
        if ((tid & 63) == 0) { s1[wave] = sum; s2[wave] = sq; }
        __syncthreads();
        float tot   = s1[0] + s1[1] + s1[2] + s1[3];
        float totsq = s2[0] + s2[1] + s2[2] + s2[3];
        float mu  = tot * (1.0f / NC);
        float var = totsq * (1.0f / NC) - mu * mu;
        float rstd = rsqrtf(var + 1e-5f);
        float4 w = ((const float4*)lnw)[tid];
        float4 o;
        o.x = (v.x - mu) * rstd * w.x;
        o.y = (v.y - mu) * rstd * w.y;
        o.z = (v.z - mu) * rstd * w.z;
        o.w = (v.w - mu) * rstd * w.w;
        ((float4*)(ns + (size_t)row * NC))[tid] = o;
    } else {
        int bx = blockIdx.x - NB * NS;
        int k0 = (bx & 15) * 64;
        int d0 = (bx >> 4) * 60;
        float (*T)[61] = (float (*)[61])sh;
        #pragma unroll
        for (int i = 0; i < 15; i++) {
            int idx = i * 256 + tid;       // 60d x 64k = 3840
            int dd = idx >> 6, kk = idx & 63;
            T[kk][dd] = wp[(size_t)(d0 + dd) * NC + k0 + kk];
        }
        __syncthreads();
        #pragma unroll
        for (int i = 0; i < 15; i++) {
            int idx = i * 256 + tid;
            int kk = idx / 60, dd = idx % 60;
            wt[(size_t)(k0 + kk) * DIMP + d0 + dd] = T[kk][dd];
        }
    }
}

// ---------------- Kernel 2: proj GEMM, LDS-staged A + 2-deep W register prefetch ----
__global__ __launch_bounds__(256) void proj_kernel(const float* __restrict__ ns,
                                                   const float* __restrict__ wt,
                                                   float* __restrict__ pp,
                                                   int use_atomic) {
    int tid = threadIdx.x;
    int wave = tid >> 6, lane = tid & 63;
    int row0 = blockIdx.x * 32;
    int ky = blockIdx.y;
    int k0 = ky * 128;

    __shared__ float A[32][128];
    #pragma unroll
    for (int i = 0; i < 4; i++) {
        int idx = tid + i * 256;          // float4 index, 1024 total
        int r = idx >> 5, c4 = idx & 31;
        *(float4*)&A[r][c4 * 4] = *(const float4*)(ns + (size_t)(row0 + r) * NC + k0 + c4 * 4);
    }
    __syncthreads();

    int wr0 = wave * 8;
    int c0 = lane * 4;
    bool active = c0 < DIMP;
    int c0m = active ? c0 : (DIMP - 4);
    const float* wb = wt + (size_t)k0 * DIMP + c0m;

    float acc[8][4];
    #pragma unroll
    for (int r = 0; r < 8; r++)
        #pragma unroll
        for (int c = 0; c < 4; c++) acc[r][c] = 0.0f;

    float4 wa[4], wx[4];
    #pragma unroll
    for (int j = 0; j < 4; j++) wa[j] = *(const float4*)(wb + (size_t)j * DIMP);

    for (int g = 0; g < 32; g += 2) {
        #pragma unroll
        for (int j = 0; j < 4; j++)
            wx[j] = *(const float4*)(wb + (size_t)((g + 1) * 4 + j) * DIMP);
        #pragma unroll
        for (int r = 0; r < 8; r++) {
            float4 a4 = *(const float4*)&A[wr0 + r][g * 4];
            #pragma unroll
            for (int c = 0; c < 4; c++) {
                float* ac = &acc[r][c];
                *ac = fmaf(a4.x, ((const float*)&wa[0])[c], *ac);
                *ac = fmaf(a4.y, ((const float*)&wa[1])[c], *ac);
                *ac = fmaf(a4.z, ((const float*)&wa[2])[c], *ac);
                *ac = fmaf(a4.w, ((const float*)&wa[3])[c], *ac);
            }
        }
        int kn2 = (g + 2 < 32) ? (g + 2) * 4 : 0;
        #pragma unroll
        for (int j = 0; j < 4; j++)
            wa[j] = *(const float4*)(wb + (size_t)(kn2 + j) * DIMP);
        #pragma unroll
        for (int r = 0; r < 8; r++) {
            float4 a4 = *(const float4*)&A[wr0 + r][(g + 1) * 4];
            #pragma unroll
            for (int c = 0; c < 4; c++) {
                float* ac = &acc[r][c];
                *ac = fmaf(a4.x, ((const float*)&wx[0])[c], *ac);
                *ac = fmaf(a4.y, ((const float*)&wx[1])[c], *ac);
                *ac = fmaf(a4.z, ((const float*)&wx[2])[c], *ac);
                *ac = fmaf(a4.w, ((const float*)&wx[3])[c], *ac);
            }
        }
    }
    if (active) {
        if (use_atomic) {
            #pragma unroll
            for (int r = 0; r < 8; r++)
                #pragma unroll
                for (int c = 0; c < 4; c++)
                    atomicAdd(&pp[(size_t)(row0 + wr0 + r) * DIMP + c0 + c], acc[r][c]);
        } else {
            float* dst = pp + (size_t)ky * (NB * NS * DIMP);
            #pragma unroll
            for (int r = 0; r < 8; r++)
                *(float4*)(dst + (size_t)(row0 + wr0 + r) * DIMP + c0) =
                    make_float4(acc[r][0], acc[r][1], acc[r][2], acc[r][3]);
        }
    }
}

// ---------------- Kernel 3: inline partial-sum + rotate + scale-fold + pack ----------
__global__ __launch_bounds__(256) void build_kernel(const float* __restrict__ pp, int nred,
                                                    const float* __restrict__ rot,
                                                    const float* __restrict__ trans,
                                                    const float* __restrict__ dist_scale,
                                                    const float* __restrict__ rot_scale,
                                                    const int* __restrict__ seq,
                                                    const int* __restrict__ chain,
                                                    const int* __restrict__ amask,
                                                    float4* __restrict__ qrb,
                                                    float4* __restrict__ qdb,
                                                    float4* __restrict__ kp) {
    int gid = blockIdx.x * 256 + threadIdx.x;   // NB*NS*80
    if (gid >= NB * NS * 80) return;
    int j  = gid % 80;
    int bs = gid / 80;
    int b  = bs >> 10;
    int si = bs & 1023;
    int off = (j < 48) ? 3 * j : 144 + 3 * (j - 48);
    float vx = 0.0f, vy = 0.0f, vz = 0.0f;
    for (int ky = 0; ky < nred; ky++) {
        const float* pr = pp + (size_t)ky * (NB * NS * DIMP) + (size_t)bs * DIMP + off;
        vx += pr[0]; vy += pr[1]; vz += pr[2];
    }
    const float* R = rot + (size_t)bs * 9;
    float ox = R[0] * vx + R[1] * vy + R[2] * vz;
    float oy = R[3] * vx + R[4] * vy + R[5] * vz;
    float oz = R[6] * vx + R[7] * vy + R[8] * vz;
    if (j >= 48) {
        ox += trans[(size_t)bs * 3 + 0];
        oy += trans[(size_t)bs * 3 + 1];
        oz += trans[(size_t)bs * 3 + 2];
    }
    if (j < 16) {
        float sc = log1pf(__expf(rot_scale[j])) * INV_SQRT3;
        float ck = (float)chain[bs] + 1000.0f * (float)(1 - amask[bs]);
        qrb[(size_t)(b * NH + j) * NS + si] = make_float4(ox * sc, oy * sc, oz * sc, ck);
    } else if (j < 32) {
        int h = j - 16;
        float ck = (float)chain[bs] + 1000.0f * (float)(1 - amask[bs]);
        kp[((size_t)(b * NH + h) * NS + si) * 3 + 0] = make_float4(ox, oy, oz, ck);
    } else if (j < 48) {
        int h = j - 32;
        kp[((size_t)(b * NH + h) * NS + si) * 3 + 2] = make_float4(ox, oy, oz, 0.0f);
    } else if (j < 64) {
        int h = j - 48;
        float sc = log1pf(__expf(dist_scale[h])) * INV_SQRT3;
        qdb[(size_t)(b * NH + h) * NS + si] =
            make_float4(ox * sc, oy * sc, oz * sc, (float)seq[bs]);
    } else {
        int h = j - 64;
        float sc = log1pf(__expf(dist_scale[h])) * INV_SQRT3;
        kp[((size_t)(b * NH + h) * NS + si) * 3 + 1] =
            make_float4(ox * sc, oy * sc, oz * sc, (float)seq[bs]);
    }
}

// ---------------- Kernel 4: attention — 2 q/thread, 8-way K-split, plain-sum partials
// grid: 32 bh x 2 qc x AKH ks = 512 blocks, 256 thr. LDS: 128 k-records (6 KB).
// Thread serves q and q+256: 3 LDS reads feed 2x the VALU work (issue-mix fix).
__global__ __launch_bounds__(256) void attn_kernel(
    const float4* __restrict__ qrb, const float4* __restrict__ qdb,
    const float4* __restrict__ kp,
    float4* __restrict__ pacc) {
    __shared__ float4 kS[384];
    int bx = blockIdx.x;
    int ks = bx & (AKH - 1), qc = (bx >> 3) & 1, bh = bx >> 4;
    int tid = threadIdx.x;
    int q1 = qc * 512 + tid;
    int q2 = q1 + 256;
    int base = bh * NS;
    const float4* kb = kp + (size_t)base * 3;

    for (int i = tid; i < 384; i += 256) kS[i] = kb[(size_t)ks * 384 + i];
    __syncthreads();

    float4 a1 = qrb[base + q1], d1 = qdb[base + q1];   // .w = cq/sq
    float4 a2 = qrb[base + q2], d2 = qdb[base + q2];
    float cq1 = a1.w, sq1 = d1.w, cq2 = a2.w, sq2 = d2.w;

    float l1 = 0, x1 = 0, y1 = 0, z1 = 0;
    float l2 = 0, x2 = 0, y2 = 0, z2 = 0;
    #pragma unroll 4
    for (int j = 0; j < 128; j++) {
        float4 f0 = kS[j * 3 + 0];
        float4 f1 = kS[j * 3 + 1];
        float4 f2 = kS[j * 3 + 2];
        {
            float rt = fmaf(a1.x, f0.x, fmaf(a1.y, f0.y, a1.z * f0.z));
            float dx = d1.x - f1.x, dy = d1.y - f1.y, dz = d1.z - f1.z;
            float dist = sqrtf(fmaf(dx, dx, fmaf(dy, dy, dz * dz)));
            float arg = fmaf(-100.0f, fabsf(f0.w - cq1), rt - dist) +
                        ((f1.w == sq1) ? -15.0f : -16.0f);
            float pw = __expf(arg);
            l1 += pw;
            x1 = fmaf(pw, f2.x, x1); y1 = fmaf(pw, f2.y, y1); z1 = fmaf(pw, f2.z, z1);
        }
        {
            float rt = fmaf(a2.x, f0.x, fmaf(a2.y, f0.y, a2.z * f0.z));
            float dx = d2.x - f1.x, dy = d2.y - f1.y, dz = d2.z - f1.z;
            float dist = sqrtf(fmaf(dx, dx, fmaf(dy, dy, dz * dz)));
            float arg = fmaf(-100.0f, fabsf(f0.w - cq2), rt - dist) +
                        ((f1.w == sq2) ? -15.0f : -16.0f);
            float pw = __expf(arg);
            l2 += pw;
            x2 = fmaf(pw, f2.x, x2); y2 = fmaf(pw, f2.y, y2); z2 = fmaf(pw, f2.z, z2);
        }
    }
    pacc[(size_t)ks * (32 * NS) + base + q1] = make_float4(x1, y1, z1, l1);
    pacc[(size_t)ks * (32 * NS) + base + q2] = make_float4(x2, y2, z2, l2);
}

// ---------------- Kernel 5: fused finalize + out-GEMM ----------------
// Thread (r = tid>>4, h = tid&15) finalizes row r0+r, head h into sm[16][48];
// then each thread computes one output column for 16 rows.
__global__ __launch_bounds__(256) void finout_kernel(const float4* __restrict__ pacc,
                                                     const float4* __restrict__ qrb,
                                                     const float* __restrict__ rot,
                                                     const float* __restrict__ wout,
                                                     float* __restrict__ out) {
    int tid = threadIdx.x;
    int c  = blockIdx.y * 256 + tid;    // 0..1023
    int r0 = blockIdx.x * 16;
    __shared__ float sm[16][48];
    {
        int r = tid >> 4, h = tid & 15;
        int row = r0 + r;                       // b*NS + q
        int b = row >> 10, q = row & 1023;
        int i = ((b * NH + h) << 10) + q;       // bh*NS + q
        float4 s4 = make_float4(0.0f, 0.0f, 0.0f, 0.0f);
        #pragma unroll
        for (int j = 0; j < AKH; j++) {
            float4 t = pacc[(size_t)j * (32 * NS) + i];
            s4.x += t.x; s4.y += t.y; s4.z += t.z; s4.w += t.w;
        }
        float inv = 1.0f / s4.w;
        float ox = s4.x * inv, oy = s4.y * inv, oz = s4.z * inv;
        const float* R = rot + (size_t)row * 9;
        float wx = R[0] * ox + R[3] * oy + R[6] * oz;
        float wy = R[1] * ox + R[4] * oy + R[7] * oz;
        float wz = R[2] * ox + R[5] * oy + R[8] * oz;
        if (qrb[i].w >= 500.0f) { wx = 0; wy = 0; wz = 0; }   // am_q == 0
        sm[r][h * 3 + 0] = wx; sm[r][h * 3 + 1] = wy; sm[r][h * 3 + 2] = wz;
    }
    __syncthreads();
    float w[48];
    #pragma unroll
    for (int d = 0; d < 48; d += 4) {
        float4 t = *(const float4*)(wout + (size_t)c * 48 + d);
        w[d] = t.x; w[d + 1] = t.y; w[d + 2] = t.z; w[d + 3] = t.w;
    }
    #pragma unroll 4
    for (int r = 0; r < 16; r++) {
        float acc = 0.0f;
        #pragma unroll
        for (int d = 0; d < 48; d++) acc = fmaf(w[d], sm[r][d], acc);
        out[(size_t)(r0 + r) * NC + c] = acc;
    }
}

extern "C" void kernel_launch(void* const* d_in, const int* in_sizes, int n_in,
                              void* d_out, int out_size, void* d_ws, size_t ws_size,
                              hipStream_t stream) {
    const float* s     = (const float*)d_in[0];
    const float* rot   = (const float*)d_in[1];
    const float* trans = (const float*)d_in[2];
    const float* lnw   = (const float*)d_in[3];
    const float* wproj = (const float*)d_in[4];
    const float* wout  = (const float*)d_in[5];
    const float* dsc   = (const float*)d_in[6];
    const float* rsc   = (const float*)d_in[7];
    const int* amask   = (const int*)d_in[8];
    const int* seq     = (const int*)d_in[9];
    const int* chain   = (const int*)d_in[10];
    float* out = (float*)d_out;

    // ws layout (floats): ns[2097152] | qrb[131072] | qdb[131072] | kp[393216] |
    //                     pp[KSPLIT x 491520]   ~= 28 MB
    // wt (983 KB) overlays qrb+qdb (dead before build writes them);
    // pacc (4 MB) overlays pp (dead after build).
    float* ns = (float*)d_ws;
    float4* qrb = (float4*)(ns + (size_t)NB * NS * NC);
    float4* qdb = qrb + (size_t)NB * NH * NS;
    float4* kpk = qdb + (size_t)NB * NH * NS;
    float* pp = (float*)(kpk + (size_t)3 * NB * NH * NS);
    float* wt = (float*)qrb;
    float4* pacc = (float4*)pp;

    size_t need = ((char*)(pp + (size_t)KSPLIT * NB * NS * DIMP)) - (char*)d_ws;
    int use_atomic = (ws_size < need) ? 1 : 0;

    pre_kernel<<<NB * NS + 64, 256, 0, stream>>>(s, lnw, ns, wproj, wt);
    if (use_atomic) {
        hipMemsetAsync(pp, 0, (size_t)NB * NS * DIMP * sizeof(float), stream);
        proj_kernel<<<dim3(64, KSPLIT), 256, 0, stream>>>(ns, wt, pp, 1);
        build_kernel<<<(NB * NS * 80 + 255) / 256, 256, 0, stream>>>(pp, 1, rot, trans, dsc, rsc,
                                                                     seq, chain, amask, qrb, qdb, kpk);
    } else {
        proj_kernel<<<dim3(64, KSPLIT), 256, 0, stream>>>(ns, wt, pp, 0);
        build_kernel<<<(NB * NS * 80 + 255) / 256, 256, 0, stream>>>(pp, KSPLIT, rot, trans, dsc, rsc,
                                                                     seq, chain, amask, qrb, qdb, kpk);
    }
    attn_kernel<<<NB * NH * 2 * AKH, 256, 0, stream>>>(qrb, qdb, kpk, pacc);
    finout_kernel<<<dim3(NB * NS / 16, 4), 256, 0, stream>>>(pacc, qrb, rot, wout, out);
}

// Round 11
// 152.876 us; speedup vs baseline: 1.0721x; 1.0721x over previous
//
#include <hip/hip_runtime.h>
#include <math.h>

#define NB 2
#define NS 1024
#define NC 1024
#define NH 16
#define DIMP 240
#define KSPLIT 16
#define AKH 16          // attention K-split

constexpr float INV_SQRT3 = 0.57735026919f;

// ---------------- Kernel 1: LayerNorm + w_proj transpose (block-split merge) ----------
__global__ __launch_bounds__(256) void pre_kernel(const float* __restrict__ s,
                                                  const float* __restrict__ lnw,
                                                  float* __restrict__ ns,
                                                  const float* __restrict__ wp,
                                                  float* __restrict__ wt) {
    __shared__ float sh[64 * 61];
    int tid = threadIdx.x;
    if (blockIdx.x < NB * NS) {
        int row = blockIdx.x;
        const float4* sp = (const float4*)(s + (size_t)row * NC);
        float4 v = sp[tid];
        float sum = v.x + v.y + v.z + v.w;
        float sq  = v.x*v.x + v.y*v.y + v.z*v.z + v.w*v.w;
        #pragma unroll
        for (int off = 32; off; off >>= 1) {
            sum += __shfl_down(sum, off);
            sq  += __shfl_down(sq, off);
        }
        float* s1 = sh; float* s2 = sh + 4;
        int wave = tid >> 6;
        if ((tid & 63) == 0) { s1[wave] = sum; s2[wave] = sq; }
        __syncthreads();
        float tot   = s1[0] + s1[1] + s1[2] + s1[3];
        float totsq = s2[0] + s2[1] + s2[2] + s2[3];
        float mu  = tot * (1.0f / NC);
        float var = totsq * (1.0f / NC) - mu * mu;
        float rstd = rsqrtf(var + 1e-5f);
        float4 w = ((const float4*)lnw)[tid];
        float4 o;
        o.x = (v.x - mu) * rstd * w.x;
        o.y = (v.y - mu) * rstd * w.y;
        o.z = (v.z - mu) * rstd * w.z;
        o.w = (v.w - mu) * rstd * w.w;
        ((float4*)(ns + (size_t)row * NC))[tid] = o;
    } else {
        int bx = blockIdx.x - NB * NS;
        int k0 = (bx & 15) * 64;
        int d0 = (bx >> 4) * 60;
        float (*T)[61] = (float (*)[61])sh;
        #pragma unroll
        for (int i = 0; i < 15; i++) {
            int idx = i * 256 + tid;       // 60d x 64k = 3840
            int dd = idx >> 6, kk = idx & 63;
            T[kk][dd] = wp[(size_t)(d0 + dd) * NC + k0 + kk];
        }
        __syncthreads();
        #pragma unroll
        for (int i = 0; i < 15; i++) {
            int idx = i * 256 + tid;
            int kk = idx / 60, dd = idx % 60;
            wt[(size_t)(k0 + kk) * DIMP + d0 + dd] = T[kk][dd];
        }
    }
}

// ---------------- Kernel 2: proj GEMM, LDS-staged A + pipelined W, KSPLIT=16 --------
__global__ __launch_bounds__(256) void proj_kernel(const float* __restrict__ ns,
                                                   const float* __restrict__ wt,
                                                   float* __restrict__ pp,
                                                   int use_atomic) {
    int tid = threadIdx.x;
    int wave = tid >> 6, lane = tid & 63;
    int row0 = blockIdx.x * 32;
    int ky = blockIdx.y;
    int k0 = ky * 64;

    __shared__ float A[32][64];
    #pragma unroll
    for (int i = 0; i < 2; i++) {
        int idx = tid + i * 256;          // float4 index, 512 total
        int r = idx >> 4, c4 = idx & 15;
        *(float4*)&A[r][c4 * 4] = *(const float4*)(ns + (size_t)(row0 + r) * NC + k0 + c4 * 4);
    }
    __syncthreads();

    int wr0 = wave * 8;
    int c0 = lane * 4;
    bool active = c0 < DIMP;
    int c0m = active ? c0 : (DIMP - 4);
    const float* wb = wt + (size_t)k0 * DIMP + c0m;

    float acc[8][4];
    #pragma unroll
    for (int r = 0; r < 8; r++)
        #pragma unroll
        for (int c = 0; c < 4; c++) acc[r][c] = 0.0f;

    float4 wa[4], wx[4];
    #pragma unroll
    for (int j = 0; j < 4; j++) wa[j] = *(const float4*)(wb + (size_t)j * DIMP);

    for (int g = 0; g < 16; g += 2) {
        #pragma unroll
        for (int j = 0; j < 4; j++)
            wx[j] = *(const float4*)(wb + (size_t)((g + 1) * 4 + j) * DIMP);
        #pragma unroll
        for (int r = 0; r < 8; r++) {
            float4 a4 = *(const float4*)&A[wr0 + r][g * 4];
            #pragma unroll
            for (int c = 0; c < 4; c++) {
                float* ac = &acc[r][c];
                *ac = fmaf(a4.x, ((const float*)&wa[0])[c], *ac);
                *ac = fmaf(a4.y, ((const float*)&wa[1])[c], *ac);
                *ac = fmaf(a4.z, ((const float*)&wa[2])[c], *ac);
                *ac = fmaf(a4.w, ((const float*)&wa[3])[c], *ac);
            }
        }
        int kn2 = (g + 2 < 16) ? (g + 2) * 4 : 0;
        #pragma unroll
        for (int j = 0; j < 4; j++)
            wa[j] = *(const float4*)(wb + (size_t)(kn2 + j) * DIMP);
        #pragma unroll
        for (int r = 0; r < 8; r++) {
            float4 a4 = *(const float4*)&A[wr0 + r][(g + 1) * 4];
            #pragma unroll
            for (int c = 0; c < 4; c++) {
                float* ac = &acc[r][c];
                *ac = fmaf(a4.x, ((const float*)&wx[0])[c], *ac);
                *ac = fmaf(a4.y, ((const float*)&wx[1])[c], *ac);
                *ac = fmaf(a4.z, ((const float*)&wx[2])[c], *ac);
                *ac = fmaf(a4.w, ((const float*)&wx[3])[c], *ac);
            }
        }
    }
    if (active) {
        if (use_atomic) {
            #pragma unroll
            for (int r = 0; r < 8; r++)
                #pragma unroll
                for (int c = 0; c < 4; c++)
                    atomicAdd(&pp[(size_t)(row0 + wr0 + r) * DIMP + c0 + c], acc[r][c]);
        } else {
            float* dst = pp + (size_t)ky * (NB * NS * DIMP);
            #pragma unroll
            for (int r = 0; r < 8; r++)
                *(float4*)(dst + (size_t)(row0 + wr0 + r) * DIMP + c0) =
                    make_float4(acc[r][0], acc[r][1], acc[r][2], acc[r][3]);
        }
    }
}

// ---------------- Kernel 3: inline partial-sum + rotate + scale-fold + pack ----------
// kpack record per (b,h,k), 3 float4s: f0=(kr.xyz, ck) f1=(kd.xyz, sk) f2=(vv.xyz, 0)
__global__ __launch_bounds__(256) void build_kernel(const float* __restrict__ pp, int nred,
                                                    const float* __restrict__ rot,
                                                    const float* __restrict__ trans,
                                                    const float* __restrict__ dist_scale,
                                                    const float* __restrict__ rot_scale,
                                                    const int* __restrict__ seq,
                                                    const int* __restrict__ chain,
                                                    const int* __restrict__ amask,
                                                    float4* __restrict__ qrb,
                                                    float4* __restrict__ qdb,
                                                    float4* __restrict__ kp) {
    int gid = blockIdx.x * 256 + threadIdx.x;   // NB*NS*80
    if (gid >= NB * NS * 80) return;
    int j  = gid % 80;
    int bs = gid / 80;
    int b  = bs >> 10;
    int si = bs & 1023;
    int off = (j < 48) ? 3 * j : 144 + 3 * (j - 48);
    float vx = 0.0f, vy = 0.0f, vz = 0.0f;
    for (int ky = 0; ky < nred; ky++) {
        const float* pr = pp + (size_t)ky * (NB * NS * DIMP) + (size_t)bs * DIMP + off;
        vx += pr[0]; vy += pr[1]; vz += pr[2];
    }
    const float* R = rot + (size_t)bs * 9;
    float ox = R[0] * vx + R[1] * vy + R[2] * vz;
    float oy = R[3] * vx + R[4] * vy + R[5] * vz;
    float oz = R[6] * vx + R[7] * vy + R[8] * vz;
    if (j >= 48) {
        ox += trans[(size_t)bs * 3 + 0];
        oy += trans[(size_t)bs * 3 + 1];
        oz += trans[(size_t)bs * 3 + 2];
    }
    if (j < 16) {
        float sc = log1pf(__expf(rot_scale[j])) * INV_SQRT3;
        qrb[(size_t)(b * NH + j) * NS + si] = make_float4(ox * sc, oy * sc, oz * sc, 0.0f);
    } else if (j < 32) {
        int h = j - 16;
        float ck = (float)chain[bs] + 1000.0f * (float)(1 - amask[bs]);
        kp[((size_t)(b * NH + h) * NS + si) * 3 + 0] = make_float4(ox, oy, oz, ck);
    } else if (j < 48) {
        int h = j - 32;
        kp[((size_t)(b * NH + h) * NS + si) * 3 + 2] = make_float4(ox, oy, oz, 0.0f);
    } else if (j < 64) {
        int h = j - 48;
        float sc = log1pf(__expf(dist_scale[h])) * INV_SQRT3;
        qdb[(size_t)(b * NH + h) * NS + si] = make_float4(ox * sc, oy * sc, oz * sc, 0.0f);
    } else {
        int h = j - 64;
        float sc = log1pf(__expf(dist_scale[h])) * INV_SQRT3;
        kp[((size_t)(b * NH + h) * NS + si) * 3 + 1] =
            make_float4(ox * sc, oy * sc, oz * sc, (float)seq[bs]);
    }
}

// ---------------- Kernel 4: attention — lane-owns-q, 16-way K-split, plain-sum partials
// grid: 32 bh x 4 qc x AKH ks = 2048 blocks, 256 thr. LDS: 64 k-records (3 KB).
__global__ __launch_bounds__(256) void attn_kernel(
    const float4* __restrict__ qrb, const float4* __restrict__ qdb,
    const float4* __restrict__ kp,
    float4* __restrict__ pacc) {
    __shared__ float4 kS[192];
    int bx = blockIdx.x;
    int ks = bx & (AKH - 1), qc = (bx >> 4) & 3, bh = bx >> 6;
    int tid = threadIdx.x;
    int q = qc * 256 + tid;
    int base = bh * NS;
    const float4* kb = kp + (size_t)base * 3;

    if (tid < 192) kS[tid] = kb[(size_t)ks * 192 + tid];
    __syncthreads();

    float4 a = qrb[base + q];
    float4 d = qdb[base + q];
    float cq = kb[(size_t)q * 3 + 0].w;
    float sq = kb[(size_t)q * 3 + 1].w;

    float l = 0.0f, ax = 0.0f, ay = 0.0f, az = 0.0f;
    #pragma unroll 4
    for (int j = 0; j < 64; j++) {
        float4 f0 = kS[j * 3 + 0];
        float4 f1 = kS[j * 3 + 1];
        float4 f2 = kS[j * 3 + 2];
        float rt = fmaf(a.x, f0.x, fmaf(a.y, f0.y, a.z * f0.z));
        float dx = d.x - f1.x, dy = d.y - f1.y, dz = d.z - f1.z;
        float dist = sqrtf(fmaf(dx, dx, fmaf(dy, dy, dz * dz)));
        float dc = f0.w - cq;
        float arg = fmaf(-100.0f, fabsf(dc), rt - dist) +
                    ((f1.w == sq) ? -15.0f : -16.0f);
        float pw = __expf(arg);   // masked (|dc|>=1) underflows to 0
        l += pw;
        ax = fmaf(pw, f2.x, ax);
        ay = fmaf(pw, f2.y, ay);
        az = fmaf(pw, f2.z, az);
    }
    pacc[(size_t)ks * (32 * NS) + base + q] = make_float4(ax, ay, az, l);
}

// ---------------- Kernel 4b: finalize — sum partials, R^T rotate, divide, mask ------
__global__ __launch_bounds__(256) void attnfin_kernel(const float4* __restrict__ pacc,
                                                      const float4* __restrict__ kp,
                                                      const float* __restrict__ rot,
                                                      float* __restrict__ small) {
    int i = blockIdx.x * 256 + threadIdx.x;   // 32*1024
    int bh = i >> 10, q = i & 1023;
    int b = bh >> 4, h = bh & 15;
    float4 s = make_float4(0.0f, 0.0f, 0.0f, 0.0f);
    #pragma unroll
    for (int j = 0; j < AKH; j++) {
        float4 t = pacc[(size_t)j * (32 * NS) + i];
        s.x += t.x; s.y += t.y; s.z += t.z; s.w += t.w;
    }
    float inv = 1.0f / s.w;
    float ox = s.x * inv, oy = s.y * inv, oz = s.z * inv;
    const float* R = rot + (size_t)(b * NS + q) * 9;
    float wx = R[0] * ox + R[3] * oy + R[6] * oz;
    float wy = R[1] * ox + R[4] * oy + R[7] * oz;
    float wz = R[2] * ox + R[5] * oy + R[8] * oz;
    float cq = kp[((size_t)bh * NS + q) * 3 + 0].w;
    if (cq >= 500.0f) { wx = 0; wy = 0; wz = 0; }   // am_q == 0
    float* o = small + (size_t)(b * NS + q) * 48 + h * 3;
    o[0] = wx; o[1] = wy; o[2] = wz;
}

// ---------------- Kernel 5: out = small @ w_out^T ----------------
__global__ __launch_bounds__(256) void outgemm_kernel(const float* __restrict__ small,
                                                      const float* __restrict__ wout,
                                                      float* __restrict__ out) {
    int c  = blockIdx.y * 256 + threadIdx.x;    // 0..1023
    int r0 = blockIdx.x * 16;
    __shared__ float sm[16][48];
    for (int i = threadIdx.x; i < 16 * 48; i += 256)
        sm[i / 48][i % 48] = small[(size_t)(r0 + i / 48) * 48 + i % 48];
    __syncthreads();
    float w[48];
    #pragma unroll
    for (int d = 0; d < 48; d += 4) {
        float4 t = *(const float4*)(wout + (size_t)c * 48 + d);
        w[d] = t.x; w[d + 1] = t.y; w[d + 2] = t.z; w[d + 3] = t.w;
    }
    #pragma unroll 4
    for (int r = 0; r < 16; r++) {
        float acc = 0.0f;
        #pragma unroll
        for (int d = 0; d < 48; d++) acc = fmaf(w[d], sm[r][d], acc);
        out[(size_t)(r0 + r) * NC + c] = acc;
    }
}

extern "C" void kernel_launch(void* const* d_in, const int* in_sizes, int n_in,
                              void* d_out, int out_size, void* d_ws, size_t ws_size,
                              hipStream_t stream) {
    const float* s     = (const float*)d_in[0];
    const float* rot   = (const float*)d_in[1];
    const float* trans = (const float*)d_in[2];
    const float* lnw   = (const float*)d_in[3];
    const float* wproj = (const float*)d_in[4];
    const float* wout  = (const float*)d_in[5];
    const float* dsc   = (const float*)d_in[6];
    const float* rsc   = (const float*)d_in[7];
    const int* amask   = (const int*)d_in[8];
    const int* seq     = (const int*)d_in[9];
    const int* chain   = (const int*)d_in[10];
    float* out = (float*)d_out;

    // ws layout (floats): ns[2097152] | qrb[131072] | qdb[131072] | kp[393216] |
    //                     small[98304] | pp[KSPLIT x 491520]   ~= 43 MB
    // wt (983 KB) overlays qrb+qdb (dead before build writes them);
    // pacc (8 MB) overlays pp (dead after build).
    float* ns = (float*)d_ws;
    float4* qrb = (float4*)(ns + (size_t)NB * NS * NC);
    float4* qdb = qrb + (size_t)NB * NH * NS;
    float4* kpk = qdb + (size_t)NB * NH * NS;
    float* small = (float*)(kpk + (size_t)3 * NB * NH * NS);
    float* pp = small + (size_t)NB * NS * 48;
    float* wt = (float*)qrb;
    float4* pacc = (float4*)pp;

    size_t need = ((char*)(pp + (size_t)KSPLIT * NB * NS * DIMP)) - (char*)d_ws;
    int use_atomic = (ws_size < need) ? 1 : 0;

    pre_kernel<<<NB * NS + 64, 256, 0, stream>>>(s, lnw, ns, wproj, wt);
    if (use_atomic) {
        hipMemsetAsync(pp, 0, (size_t)NB * NS * DIMP * sizeof(float), stream);
        proj_kernel<<<dim3(64, KSPLIT), 256, 0, stream>>>(ns, wt, pp, 1);
        build_kernel<<<(NB * NS * 80 + 255) / 256, 256, 0, stream>>>(pp, 1, rot, trans, dsc, rsc,
                                                                     seq, chain, amask, qrb, qdb, kpk);
    } else {
        proj_kernel<<<dim3(64, KSPLIT), 256, 0, stream>>>(ns, wt, pp, 0);
        build_kernel<<<(NB * NS * 80 + 255) / 256, 256, 0, stream>>>(pp, KSPLIT, rot, trans, dsc, rsc,
                                                                     seq, chain, amask, qrb, qdb, kpk);
    }
    attn_kernel<<<NB * NH * 4 * AKH, 256, 0, stream>>>(qrb, qdb, kpk, pacc);
    attnfin_kernel<<<NB * NH * NS / 256, 256, 0, stream>>>(pacc, kpk, rot, small);
    outgemm_kernel<<<dim3(NB * NS / 16, 4), 256, 0, stream>>>(small, wout, out);
}